// Round 5
// baseline (268.413 us; speedup 1.0000x reference)
//
#include <hip/hip_runtime.h>

// out[b,j,hw] = exp( sum_i log(relu(x[b,i,hw])+0.1) * E[i,j] ) + bias[j]
// x: (B=32, NC=64, H=128, W=128) fp32.
#define NCH 64
#define JT 32                  // output-channel tile per pass
#define NPASS (NCH / JT)       // 2 passes; jt stays a RUNTIME loop so only
                               // 32 accumulators are live (R4: 64 live accs
                               // pushed into AGPRs -> 4 waves/SIMD, 104 us)
#define HWSZ 16384             // 128*128
#define NPOINTS (32 * HWSZ)    // 524288

__global__ __launch_bounds__(256, 4) void fused_log_einsum_exp(
    const float* __restrict__ x,
    const float* __restrict__ E,     // (64,64) row-major: E[i*64+j]
    const float* __restrict__ bias,  // (64)
    float* __restrict__ out)
{
    const int p  = blockIdx.x * 256 + threadIdx.x;  // one spatial point/thread
    const int b  = p >> 14;          // p / HWSZ
    const int hw = p & (HWSZ - 1);   // p % HWSZ

    const float* xp = x   + (size_t)b * NCH * HWSZ + hw;
    float*       op = out + (size_t)b * NCH * HWSZ + hw;

    // jt MUST stay a runtime loop (no unroll): unrolling would make both
    // passes' accumulators simultaneously live again (the R4 AGPR trap).
    #pragma unroll 1
    for (int jt = 0; jt < NPASS; ++jt) {
        const float* Ej = E + jt * JT;   // uniform -> SMEM s_load chunks

        float acc[JT];
        #pragma unroll
        for (int j = 0; j < JT; ++j) acc[j] = 0.0f;   // static idx (SROA)

        // Per i: one coalesced 4B/lane load, one log, 32 fmacs against a
        // 128 B SGPR chunk of E. unroll 4 => 4 x-loads + 4 E-chunks in
        // flight; 8 waves/SIMD hides the rest. Pass 2 re-reads x from L2/L3.
        #pragma unroll 4
        for (int i = 0; i < NCH; ++i) {
            float v  = xp[(size_t)i * HWSZ];
            float lx = __logf(fmaxf(v, 0.0f) + 0.1f);
            #pragma unroll
            for (int j = 0; j < JT; ++j)
                acc[j] = fmaf(lx, Ej[i * NCH + j], acc[j]);
        }

        // Epilogue: exp + bias (uniform SMEM), coalesced 256B/wave stores.
        #pragma unroll
        for (int j = 0; j < JT; ++j)
            op[(size_t)(jt * JT + j) * HWSZ] = __expf(acc[j]) + bias[jt * JT + j];
    }
}

extern "C" void kernel_launch(void* const* d_in, const int* in_sizes, int n_in,
                              void* d_out, int out_size, void* d_ws, size_t ws_size,
                              hipStream_t stream) {
    const float* x    = (const float*)d_in[0];
    const float* E    = (const float*)d_in[1];   // (64,64,1,1) -> [i*64+j]
    const float* bias = (const float*)d_in[2];   // (64,1,1)
    float* out = (float*)d_out;

    dim3 grid(NPOINTS / 256), block(256);
    hipLaunchKernelGGL(fused_log_einsum_exp, grid, block, 0, stream,
                       x, E, bias, out);
}